// Round 6
// baseline (252.042 us; speedup 1.0000x reference)
//
#include <hip/hip_runtime.h>
#include <hip/hip_bf16.h>

typedef short bs8 __attribute__((ext_vector_type(8)));
typedef short bs4 __attribute__((ext_vector_type(4)));
typedef float f32x4 __attribute__((ext_vector_type(4)));
typedef float f32x16 __attribute__((ext_vector_type(16)));
typedef int i32x4 __attribute__((ext_vector_type(4)));

#define B_ 4
#define L_ 2048
#define H_ 16
#define E_ 64
#define KT_ 64    // keys per logical tile (two 32-key halves, one per wave-group)
#define SCSTR 68  // f32 stride for combine/transpose scratch
#define NEG_INF (-1e30f)
#define SCALE_LOG2E (0.125f * 1.44269504088896340736f)

__device__ __forceinline__ short bf16of(float x) {
  __hip_bfloat16 h = __float2bfloat16(x);
  return *reinterpret_cast<short*>(&h);
}

// ---------- Fused prepass (unchanged) ----------
// blocks [0,1024):    K fp32 [b,s,h,e] -> bf16 Kb [bh,s,e]   (grid-stride x8)
// blocks [1024,3072): V fp32 [b,s,h,e] -> bf16 Vt [bh,e,s]   (packed-u32 LDS transpose)
__global__ __launch_bounds__(256) void prep(const float* __restrict__ K,
                                            const float* __restrict__ V,
                                            short* __restrict__ Kb,
                                            short* __restrict__ Vt) {
  __shared__ unsigned int lt[64 * 35];   // [e][s_pair] packed 2x bf16
  const int tid = threadIdx.x;
  if (blockIdx.x < 1024) {
    size_t base = (size_t)blockIdx.x * 256 + tid;
#pragma unroll
    for (int i = 0; i < 8; ++i) {
      size_t g = base + (size_t)i * 262144;   // float4 index
      int e4 = g & 15;
      int h  = (g >> 4) & 15;
      int s  = (g >> 8) & 2047;
      int b  = (int)(g >> 19);
      float4 v = *(const float4*)(K + g * 4);
      bs4 o;
      o.x = bf16of(v.x); o.y = bf16of(v.y); o.z = bf16of(v.z); o.w = bf16of(v.w);
      *(bs4*)(Kb + (((size_t)(b * 16 + h) * L_ + s) * E_ + e4 * 4)) = o;
    }
  } else {
    int vb = blockIdx.x - 1024;   // 0..2047
    int st = vb & 31, bh = vb >> 5;
    int b = bh >> 4, h = bh & 15;
    int s0 = st * 64;
#pragma unroll
    for (int i = 0; i < 2; ++i) {
      int idx = i * 256 + tid;       // 0..511
      int sp = idx >> 4;             // s-pair 0..31
      int e4 = idx & 15;
      const float* p0 = V + (((size_t)b * L_ + s0 + 2 * sp) * H_ + h) * E_ + e4 * 4;
      float4 v0 = *(const float4*)p0;
      float4 v1 = *(const float4*)(p0 + H_ * E_);
      unsigned u;
      u = (unsigned short)bf16of(v0.x) | ((unsigned)(unsigned short)bf16of(v1.x) << 16);
      lt[(e4 * 4 + 0) * 35 + sp] = u;
      u = (unsigned short)bf16of(v0.y) | ((unsigned)(unsigned short)bf16of(v1.y) << 16);
      lt[(e4 * 4 + 1) * 35 + sp] = u;
      u = (unsigned short)bf16of(v0.z) | ((unsigned)(unsigned short)bf16of(v1.z) << 16);
      lt[(e4 * 4 + 2) * 35 + sp] = u;
      u = (unsigned short)bf16of(v0.w) | ((unsigned)(unsigned short)bf16of(v1.w) << 16);
      lt[(e4 * 4 + 3) * 35 + sp] = u;
    }
    __syncthreads();
#pragma unroll
    for (int i = 0; i < 2; ++i) {
      int idx = i * 256 + tid;
      int e  = idx >> 3;             // 0..63
      int s8 = idx & 7;              // 8-key group
      uint4 o;
      o.x = lt[e * 35 + s8 * 4 + 0];
      o.y = lt[e * 35 + s8 * 4 + 1];
      o.z = lt[e * 35 + s8 * 4 + 2];
      o.w = lt[e * 35 + s8 * 4 + 3];
      *(uint4*)(Vt + ((size_t)bh * E_ + e) * L_ + s0 + 8 * s8) = o;
    }
  }
}

// ---------- Main flash-attention kernel ----------
// Grid 1024, 256 threads (4 waves). Block = 64 q-rows, q-tile pair {p,31-p}
// in two phases: 33 tiles per block -> every block identical (structural
// balance; grid == resident capacity so no backfill exists). 4 blocks/CU
// resident = 16 waves/CU.
// NO K/V LDS staging (r5 lesson / m169): per-XCD working set = 8 bh x 512KB
// = 4MB = exactly one XCD L2. A-frags read directly from Kb/Vt (L2-hot);
// zero barriers in the K-loop -> compiler pipelines loads across tiles.
// Wave (g,s): s = row strip [q0+32s,+32), g = key half [k0+32g,+32).
// Unnormalized exp2-domain partials combined across g via LDS at phase end.
// XCD decode: id&7 = XCD; each XCD works bh in [x*8, x*8+8).
//
// Swapped QK^T (T12): S^T = K.Q^T via mfma_32x32x16 (A=K, B=Q regs) ->
// lane holds P^T[key][q=l32] for its 16 key-rows. Mask + exp2
// (__builtin_amdgcn_exp2f = raw v_exp_f32; -1e30 -> 0) + pack via inline
// v_cvt_pk_bf16_f32 + 2x2 v_permlane32_swap (distinct-value operands only;
// identical inputs tie to one vreg -> vdst==src0 miscompile, the r3 bug).
// O^T = V^T.P^T. No P LDS round-trip, no fence.
// 32x32x16 layouts (m74/m101 verified):
//   A[m = lane&31][k = (lane>>5)*8 + j]
//   B[k = (lane>>5)*8 + j][n = lane&31]
//   C/D: col = lane&31, row = (reg&3) + 8*(reg>>2) + 4*(lane>>5)
__global__ __launch_bounds__(256, 4) void flash_fwd(const float* __restrict__ Q,
                                                    const short* __restrict__ Kb,
                                                    const short* __restrict__ Vt,
                                                    float* __restrict__ O) {
  const int id  = blockIdx.x;
  const int xcd = id & 7;
  const int j   = id >> 3;               // 0..127 within XCD
  const int bh  = xcd * 8 + (j >> 4);
  const int p   = j & 15;                // pair {p, 31-p}
  const int b = bh >> 4, h = bh & 15;
  const int tid = threadIdx.x;
  const int w = tid >> 6;
  const int g = w >> 1;                  // key half-group
  const int s = w & 1;                   // row strip
  const int lane = tid & 63;
  const int l32 = lane & 31;
  const int hh  = lane >> 5;
  const int h8  = hh * 8;

  __shared__ float scb[2 * 32 * SCSTR + 64];   // combine/transpose scratch only

  const short* KbBase = Kb + (size_t)bh * L_ * E_;
  const short* VtBase = Vt + (size_t)bh * E_ * L_;

  for (int phase = 0; phase < 2; ++phase) {
    const int qt  = phase ? (31 - p) : p;
    const int q0w = qt * 64 + 32 * s;    // this wave's first q row
    const int nkt = qt + 1;

    // ---- Q B-frags: aQ[ks] covers dims ks*16 + h8 .. +7 (pre-scaled) ----
    bs8 aQ[4];
    {
      const float* qp = Q + (((size_t)b * L_ + q0w + l32) * H_ + h) * E_ + h8;
#pragma unroll
      for (int ks = 0; ks < 4; ++ks) {
        float4 f0 = *(const float4*)(qp + ks * 16);
        float4 f1 = *(const float4*)(qp + ks * 16 + 4);
        bs8 a;
        a[0] = bf16of(f0.x * SCALE_LOG2E); a[1] = bf16of(f0.y * SCALE_LOG2E);
        a[2] = bf16of(f0.z * SCALE_LOG2E); a[3] = bf16of(f0.w * SCALE_LOG2E);
        a[4] = bf16of(f1.x * SCALE_LOG2E); a[5] = bf16of(f1.y * SCALE_LOG2E);
        a[6] = bf16of(f1.z * SCALE_LOG2E); a[7] = bf16of(f1.w * SCALE_LOG2E);
        aQ[ks] = a;
      }
    }

    f32x16 accO[2];            // O^T partial (this g's keys): [dsub]
#pragma unroll
    for (int d = 0; d < 2; ++d)
#pragma unroll
      for (int r = 0; r < 16; ++r) accO[d][r] = 0.f;
    float accL = 0.f;          // denominator partial

    for (int kt = 0; kt < nkt; ++kt) {
      const int kb = kt * KT_ + 32 * g;    // this wave's 32-key half
      if (kb > q0w + 31) continue;         // fully masked (only g=1,s=0 last tile)
      const bool diag = (kb + 31 > q0w);

      // ---- S^T = K.Q^T directly from global (L2-hot) ----
      f32x16 cc;
#pragma unroll
      for (int r = 0; r < 16; ++r) cc[r] = 0.f;
      const short* kp = KbBase + (size_t)(kb + l32) * E_ + h8;
#pragma unroll
      for (int ks = 0; ks < 4; ++ks) {
        bs8 aK = *(const bs8*)(kp + ks * 16);
        cc = __builtin_amdgcn_mfma_f32_32x32x16_bf16(aK, aQ[ks], cc, 0, 0, 0);
      }
      if (diag) {
        const int qcol = q0w + l32;
#pragma unroll
        for (int r = 0; r < 16; ++r) {
          const int key = kb + ((r & 3) + 8 * (r >> 2) + 4 * hh);
          if (key > qcol) cc[r] = NEG_INF;
        }
      }
      // ---- exp2 (raw v_exp_f32), denominator, pack ----
      float pv[16];
#pragma unroll
      for (int r = 0; r < 16; ++r) pv[r] = __builtin_amdgcn_exp2f(cc[r]);
      accL += ((((pv[0] + pv[1]) + (pv[2] + pv[3])) + ((pv[4] + pv[5]) + (pv[6] + pv[7]))) +
               (((pv[8] + pv[9]) + (pv[10] + pv[11])) + ((pv[12] + pv[13]) + (pv[14] + pv[15]))));
      unsigned pk[8];
#pragma unroll
      for (int i = 0; i < 8; ++i)
        asm("v_cvt_pk_bf16_f32 %0, %1, %2"
            : "=v"(pk[i]) : "v"(pv[2 * i]), "v"(pv[2 * i + 1]));
      unsigned w0 = pk[0], w2 = pk[2];
      asm("v_permlane32_swap_b32 %0, %1" : "+v"(w0), "+v"(w2));
      unsigned w1 = pk[1], w3 = pk[3];
      asm("v_permlane32_swap_b32 %0, %1" : "+v"(w1), "+v"(w3));
      unsigned w4 = pk[4], w6 = pk[6];
      asm("v_permlane32_swap_b32 %0, %1" : "+v"(w4), "+v"(w6));
      unsigned w5 = pk[5], w7 = pk[7];
      asm("v_permlane32_swap_b32 %0, %1" : "+v"(w5), "+v"(w7));
      i32x4 f0 = {(int)w0, (int)w1, (int)w2, (int)w3};
      i32x4 f1 = {(int)w4, (int)w5, (int)w6, (int)w7};
      bs8 pB0 = *(bs8*)&f0;
      bs8 pB1 = *(bs8*)&f1;

      // ---- O^T += V^T . P^T (V^T frags directly from global) ----
#pragma unroll
      for (int dsub = 0; dsub < 2; ++dsub) {
        const short* vp = VtBase + (size_t)(dsub * 32 + l32) * L_ + kb + h8;
        bs8 aV0 = *(const bs8*)(vp);
        bs8 aV1 = *(const bs8*)(vp + 16);
        accO[dsub] = __builtin_amdgcn_mfma_f32_32x32x16_bf16(aV0, pB0, accO[dsub], 0, 0, 0);
        accO[dsub] = __builtin_amdgcn_mfma_f32_32x32x16_bf16(aV1, pB1, accO[dsub], 0, 0, 0);
      }
    }

    // ---- combine across g (unnormalized partials add exactly), store ----
    const float Lf = accL + __shfl_xor(accL, 32, 64);
    __syncthreads();   // also orders prior phase's scratch reads
    float* scbO = scb + s * (32 * SCSTR);
    float* scbL = scb + 2 * (32 * SCSTR) + s * 32;
    if (g == 1) {
#pragma unroll
      for (int dsub = 0; dsub < 2; ++dsub)
#pragma unroll
        for (int q4 = 0; q4 < 4; ++q4) {
          f32x4 vv = {accO[dsub][4 * q4 + 0], accO[dsub][4 * q4 + 1],
                      accO[dsub][4 * q4 + 2], accO[dsub][4 * q4 + 3]};
          *(f32x4*)&scbO[(size_t)l32 * SCSTR + dsub * 32 + 8 * q4 + 4 * hh] = vv;
        }
      if (hh == 0) scbL[l32] = Lf;
    }
    __syncthreads();
    if (g == 0) {
      const float inv = 1.f / (Lf + scbL[l32]);
#pragma unroll
      for (int dsub = 0; dsub < 2; ++dsub)
#pragma unroll
        for (int q4 = 0; q4 < 4; ++q4) {
          float* ptr = &scbO[(size_t)l32 * SCSTR + dsub * 32 + 8 * q4 + 4 * hh];
          f32x4 ov = *(const f32x4*)ptr;
          f32x4 vv = {(accO[dsub][4 * q4 + 0] + ov.x) * inv,
                      (accO[dsub][4 * q4 + 1] + ov.y) * inv,
                      (accO[dsub][4 * q4 + 2] + ov.z) * inv,
                      (accO[dsub][4 * q4 + 3] + ov.w) * inv};
          *(f32x4*)ptr = vv;
        }
      // transposed coalesced store: 4 full q-rows per instruction
#pragma unroll
      for (int jj = 0; jj < 8; ++jj) {
        const int qq = jj * 4 + (lane >> 4);
        const int d0 = (lane & 15) * 4;
        f32x4 ov = *(const f32x4*)&scbO[(size_t)qq * SCSTR + d0];
        float* op = O + (((size_t)b * L_ + qt * 64 + 32 * s + qq) * H_ + h) * E_ + d0;
        *(f32x4*)op = ov;
      }
    }
  }
}

extern "C" void kernel_launch(void* const* d_in, const int* in_sizes, int n_in,
                              void* d_out, int out_size, void* d_ws, size_t ws_size,
                              hipStream_t stream) {
  (void)in_sizes; (void)n_in; (void)out_size; (void)ws_size;
  const float* Q = (const float*)d_in[0];
  const float* K = (const float*)d_in[1];
  const float* V = (const float*)d_in[2];
  float* Out = (float*)d_out;
  short* Kb = (short*)d_ws;                              // 16.78 MB
  short* Vt = Kb + (size_t)B_ * H_ * L_ * E_;            // +16.78 MB

  prep<<<1024 + 2048, 256, 0, stream>>>(K, V, Kb, Vt);
  flash_fwd<<<1024, 256, 0, stream>>>(Q, Kb, Vt, Out);
}

// Round 7
// 187.611 us; speedup vs baseline: 1.3434x; 1.3434x over previous
//
#include <hip/hip_runtime.h>
#include <hip/hip_bf16.h>

typedef short bs8 __attribute__((ext_vector_type(8)));
typedef short bs4 __attribute__((ext_vector_type(4)));
typedef float f32x4 __attribute__((ext_vector_type(4)));
typedef float f32x16 __attribute__((ext_vector_type(16)));
typedef int i32x4 __attribute__((ext_vector_type(4)));

#define B_ 4
#define L_ 2048
#define H_ 16
#define E_ 64
#define KT_ 64    // keys per staged tile (two 32-key halves, one per wave-group)
#define KSTR 72   // LDS stride (shorts) for K/V rows
#define SCSTR 68  // f32 stride for combine/transpose scratch
#define NEG_INF (-1e30f)
#define SCALE_LOG2E (0.125f * 1.44269504088896340736f)

__device__ __forceinline__ short bf16of(float x) {
  __hip_bfloat16 h = __float2bfloat16(x);
  return *reinterpret_cast<short*>(&h);
}

// ---------- Fused prepass (unchanged) ----------
// blocks [0,1024):    K fp32 [b,s,h,e] -> bf16 Kb [bh,s,e]   (grid-stride x8)
// blocks [1024,3072): V fp32 [b,s,h,e] -> bf16 Vt [bh,e,s]   (packed-u32 LDS transpose)
__global__ __launch_bounds__(256) void prep(const float* __restrict__ K,
                                            const float* __restrict__ V,
                                            short* __restrict__ Kb,
                                            short* __restrict__ Vt) {
  __shared__ unsigned int lt[64 * 35];   // [e][s_pair] packed 2x bf16
  const int tid = threadIdx.x;
  if (blockIdx.x < 1024) {
    size_t base = (size_t)blockIdx.x * 256 + tid;
#pragma unroll
    for (int i = 0; i < 8; ++i) {
      size_t g = base + (size_t)i * 262144;   // float4 index
      int e4 = g & 15;
      int h  = (g >> 4) & 15;
      int s  = (g >> 8) & 2047;
      int b  = (int)(g >> 19);
      float4 v = *(const float4*)(K + g * 4);
      bs4 o;
      o.x = bf16of(v.x); o.y = bf16of(v.y); o.z = bf16of(v.z); o.w = bf16of(v.w);
      *(bs4*)(Kb + (((size_t)(b * 16 + h) * L_ + s) * E_ + e4 * 4)) = o;
    }
  } else {
    int vb = blockIdx.x - 1024;   // 0..2047
    int st = vb & 31, bh = vb >> 5;
    int b = bh >> 4, h = bh & 15;
    int s0 = st * 64;
#pragma unroll
    for (int i = 0; i < 2; ++i) {
      int idx = i * 256 + tid;       // 0..511
      int sp = idx >> 4;             // s-pair 0..31
      int e4 = idx & 15;
      const float* p0 = V + (((size_t)b * L_ + s0 + 2 * sp) * H_ + h) * E_ + e4 * 4;
      float4 v0 = *(const float4*)p0;
      float4 v1 = *(const float4*)(p0 + H_ * E_);
      unsigned u;
      u = (unsigned short)bf16of(v0.x) | ((unsigned)(unsigned short)bf16of(v1.x) << 16);
      lt[(e4 * 4 + 0) * 35 + sp] = u;
      u = (unsigned short)bf16of(v0.y) | ((unsigned)(unsigned short)bf16of(v1.y) << 16);
      lt[(e4 * 4 + 1) * 35 + sp] = u;
      u = (unsigned short)bf16of(v0.z) | ((unsigned)(unsigned short)bf16of(v1.z) << 16);
      lt[(e4 * 4 + 2) * 35 + sp] = u;
      u = (unsigned short)bf16of(v0.w) | ((unsigned)(unsigned short)bf16of(v1.w) << 16);
      lt[(e4 * 4 + 3) * 35 + sp] = u;
    }
    __syncthreads();
#pragma unroll
    for (int i = 0; i < 2; ++i) {
      int idx = i * 256 + tid;
      int e  = idx >> 3;             // 0..63
      int s8 = idx & 7;              // 8-key group
      uint4 o;
      o.x = lt[e * 35 + s8 * 4 + 0];
      o.y = lt[e * 35 + s8 * 4 + 1];
      o.z = lt[e * 35 + s8 * 4 + 2];
      o.w = lt[e * 35 + s8 * 4 + 3];
      *(uint4*)(Vt + ((size_t)bh * E_ + e) * L_ + s0 + 8 * s8) = o;
    }
  }
}

// ---------- Main flash-attention kernel ----------
// r7 = r5's staging/prefetch structure (benched 87.8us, race-clean) +
// r6's verified VALU cuts (raw v_exp_f32, v_cvt_pk_bf16_f32) + setprio
// around MFMA clusters (T5: applies when co-resident blocks are at
// independent phases; 4 blocks/CU here).
// r6 lesson: reg-staging IS the latency pipeline (batched prefetch ahead
// of a barrier) -- removing it exposed serial L2 latency chains (142us,
// both pipes <15%). m169's "drop staging" requires a redundant copy, not
// a decoupling one.
//
// Grid 1024, 256 threads (4 waves). Block = 64 q-rows, pair {p, 31-p} in
// two phases: 33 tiles per block -> every block identical (structural
// balance; grid == resident capacity, no backfill). 4 blocks/CU resident.
// Wave (g,s): s = row strip [q0+32s,+32), g = key half [k0+32g,+32).
// Unnormalized exp2-domain partials combined across g via LDS at phase end.
// XCD decode: id&7 = XCD; each XCD works bh in [x*8, x*8+8) (4MB = L2).
//
// Swapped QK^T (T12): S^T = K.Q^T via mfma_32x32x16 (A=K from LDS, B=Q in
// regs) -> lane holds P^T[key][q=l32] for its 16 key-rows. Mask + exp2 +
// pack in-register via v_cvt_pk_bf16_f32 + 2x2 v_permlane32_swap
// (distinct-value operands only; identical inputs tie to one vreg ->
// vdst==src0 miscompile, the r3 inf bug). O^T = V^T.P^T (A=V^T from LDS).
// 32x32x16 layouts (m74/m101 verified):
//   A[m = lane&31][k = (lane>>5)*8 + j]
//   B[k = (lane>>5)*8 + j][n = lane&31]
//   C/D: col = lane&31, row = (reg&3) + 8*(reg>>2) + 4*(lane>>5)
__global__ __launch_bounds__(256, 4) void flash_fwd(const float* __restrict__ Q,
                                                    const short* __restrict__ Kb,
                                                    const short* __restrict__ Vt,
                                                    float* __restrict__ O) {
  const int id  = blockIdx.x;
  const int xcd = id & 7;
  const int j   = id >> 3;               // 0..127 within XCD
  const int bh  = xcd * 8 + (j >> 4);
  const int p   = j & 15;                // pair {p, 31-p}
  const int b = bh >> 4, h = bh & 15;
  const int tid = threadIdx.x;
  const int w = tid >> 6;
  const int g = w >> 1;                  // key half-group: keys [k0+32g, +32)
  const int s = w & 1;                   // row strip
  const int lane = tid & 63;
  const int l32 = lane & 31;
  const int hh  = lane >> 5;
  const int h8  = hh * 8;

  // tile staging (18.4 KB) unioned with combine/transpose scratch (17.7 KB)
  __shared__ __align__(16) char smem[18432];
  short* ldsK = (short*)smem;                       // [64 keys][KSTR]
  short* ldsV = (short*)(smem + KT_ * KSTR * 2);    // [64 dims][KSTR]
  float* scb  = (float*)smem;                       // combine scratch

  const short* KbBase = Kb + (size_t)bh * L_ * E_;
  const short* VtBase = Vt + (size_t)bh * E_ * L_;

  // staging coords: rows sr, sr+32; cols sc8..sc8+7
  const int sr = tid >> 3;
  const int sc8 = (tid & 7) * 8;

  for (int phase = 0; phase < 2; ++phase) {
    const int qt  = phase ? (31 - p) : p;
    const int q0w = qt * 64 + 32 * s;    // this wave's first q row
    const int nkt = qt + 1;

    // ---- Q B-frags: aQ[ks] covers dims ks*16 + h8 .. +7 (pre-scaled) ----
    bs8 aQ[4];
    {
      const float* qp = Q + (((size_t)b * L_ + q0w + l32) * H_ + h) * E_ + h8;
#pragma unroll
      for (int ks = 0; ks < 4; ++ks) {
        float4 f0 = *(const float4*)(qp + ks * 16);
        float4 f1 = *(const float4*)(qp + ks * 16 + 4);
        bs8 a;
        a[0] = bf16of(f0.x * SCALE_LOG2E); a[1] = bf16of(f0.y * SCALE_LOG2E);
        a[2] = bf16of(f0.z * SCALE_LOG2E); a[3] = bf16of(f0.w * SCALE_LOG2E);
        a[4] = bf16of(f1.x * SCALE_LOG2E); a[5] = bf16of(f1.y * SCALE_LOG2E);
        a[6] = bf16of(f1.z * SCALE_LOG2E); a[7] = bf16of(f1.w * SCALE_LOG2E);
        aQ[ks] = a;
      }
    }

    f32x16 accO[2];            // O^T partial (this g's keys): [dsub]
#pragma unroll
    for (int d = 0; d < 2; ++d)
#pragma unroll
      for (int r = 0; r < 16; ++r) accO[d][r] = 0.f;
    float accL = 0.f;          // denominator partial

    // ---- prefetch tile 0 ----
    bs8 pfK[2], pfV[2];
#pragma unroll
    for (int i = 0; i < 2; ++i) {
      pfK[i] = *(const bs8*)(KbBase + (size_t)(sr + 32 * i) * E_ + sc8);
      pfV[i] = *(const bs8*)(VtBase + (size_t)(sr + 32 * i) * L_ + sc8);
    }

    for (int kt = 0; kt < nkt; ++kt) {
      const int k0 = kt * KT_;
      __syncthreads();   // previous tile's LDS reads (or scratch reads) done
#pragma unroll
      for (int i = 0; i < 2; ++i) {
        *(bs8*)&ldsK[(sr + 32 * i) * KSTR + sc8] = pfK[i];
        *(bs8*)&ldsV[(sr + 32 * i) * KSTR + sc8] = pfV[i];
      }
      if (kt + 1 < nkt) {
        const int kn = k0 + KT_;
#pragma unroll
        for (int i = 0; i < 2; ++i) {
          pfK[i] = *(const bs8*)(KbBase + (size_t)(kn + sr + 32 * i) * E_ + sc8);
          pfV[i] = *(const bs8*)(VtBase + (size_t)(sr + 32 * i) * L_ + kn + sc8);
        }
      }
      __syncthreads();

      const int kb = k0 + 32 * g;          // this wave's 32-key half
      if (kb <= q0w + 31) {                // not fully masked
        const bool diag = (kb + 31 > q0w);

        // ---- S^T = K.Q^T on this half ----
        f32x16 cc;
#pragma unroll
        for (int r = 0; r < 16; ++r) cc[r] = 0.f;
        __builtin_amdgcn_s_setprio(1);
#pragma unroll
        for (int ks = 0; ks < 4; ++ks) {
          bs8 aK = *(const bs8*)&ldsK[(32 * g + l32) * KSTR + ks * 16 + h8];
          cc = __builtin_amdgcn_mfma_f32_32x32x16_bf16(aK, aQ[ks], cc, 0, 0, 0);
        }
        __builtin_amdgcn_s_setprio(0);
        if (diag) {
          const int qcol = q0w + l32;
#pragma unroll
          for (int r = 0; r < 16; ++r) {
            const int key = kb + ((r & 3) + 8 * (r >> 2) + 4 * hh);
            if (key > qcol) cc[r] = NEG_INF;
          }
        }
        // ---- exp2 (raw v_exp_f32), denominator, pack (cvt_pk) ----
        float pv[16];
#pragma unroll
        for (int r = 0; r < 16; ++r) pv[r] = __builtin_amdgcn_exp2f(cc[r]);
        accL += ((((pv[0] + pv[1]) + (pv[2] + pv[3])) + ((pv[4] + pv[5]) + (pv[6] + pv[7]))) +
                 (((pv[8] + pv[9]) + (pv[10] + pv[11])) + ((pv[12] + pv[13]) + (pv[14] + pv[15]))));
        unsigned pk[8];
#pragma unroll
        for (int i = 0; i < 8; ++i)
          asm("v_cvt_pk_bf16_f32 %0, %1, %2"
              : "=v"(pk[i]) : "v"(pv[2 * i]), "v"(pv[2 * i + 1]));
        unsigned w0 = pk[0], w2 = pk[2];
        asm("v_permlane32_swap_b32 %0, %1" : "+v"(w0), "+v"(w2));
        unsigned w1 = pk[1], w3 = pk[3];
        asm("v_permlane32_swap_b32 %0, %1" : "+v"(w1), "+v"(w3));
        unsigned w4 = pk[4], w6 = pk[6];
        asm("v_permlane32_swap_b32 %0, %1" : "+v"(w4), "+v"(w6));
        unsigned w5 = pk[5], w7 = pk[7];
        asm("v_permlane32_swap_b32 %0, %1" : "+v"(w5), "+v"(w7));
        i32x4 f0 = {(int)w0, (int)w1, (int)w2, (int)w3};
        i32x4 f1 = {(int)w4, (int)w5, (int)w6, (int)w7};
        bs8 pB0 = *(bs8*)&f0;
        bs8 pB1 = *(bs8*)&f1;

        // ---- O^T += V^T . P^T (this g's 32 keys) ----
        __builtin_amdgcn_s_setprio(1);
#pragma unroll
        for (int dsub = 0; dsub < 2; ++dsub) {
          bs8 aV0 = *(const bs8*)&ldsV[(dsub * 32 + l32) * KSTR + 32 * g + h8];
          bs8 aV1 = *(const bs8*)&ldsV[(dsub * 32 + l32) * KSTR + 32 * g + 16 + h8];
          accO[dsub] = __builtin_amdgcn_mfma_f32_32x32x16_bf16(aV0, pB0, accO[dsub], 0, 0, 0);
          accO[dsub] = __builtin_amdgcn_mfma_f32_32x32x16_bf16(aV1, pB1, accO[dsub], 0, 0, 0);
        }
        __builtin_amdgcn_s_setprio(0);
      }
    }

    // ---- combine across g (unnormalized partials add exactly), store ----
    const float Lf = accL + __shfl_xor(accL, 32, 64);
    __syncthreads();   // all tile LDS reads done; smem -> scratch
    float* scbO = scb + s * (32 * SCSTR);
    float* scbL = scb + 2 * (32 * SCSTR) + s * 32;
    if (g == 1) {
#pragma unroll
      for (int dsub = 0; dsub < 2; ++dsub)
#pragma unroll
        for (int q4 = 0; q4 < 4; ++q4) {
          f32x4 vv = {accO[dsub][4 * q4 + 0], accO[dsub][4 * q4 + 1],
                      accO[dsub][4 * q4 + 2], accO[dsub][4 * q4 + 3]};
          *(f32x4*)&scbO[(size_t)l32 * SCSTR + dsub * 32 + 8 * q4 + 4 * hh] = vv;
        }
      if (hh == 0) scbL[l32] = Lf;
    }
    __syncthreads();
    if (g == 0) {
      const float inv = 1.f / (Lf + scbL[l32]);
#pragma unroll
      for (int dsub = 0; dsub < 2; ++dsub)
#pragma unroll
        for (int q4 = 0; q4 < 4; ++q4) {
          float* ptr = &scbO[(size_t)l32 * SCSTR + dsub * 32 + 8 * q4 + 4 * hh];
          f32x4 ov = *(const f32x4*)ptr;
          f32x4 vv = {(accO[dsub][4 * q4 + 0] + ov.x) * inv,
                      (accO[dsub][4 * q4 + 1] + ov.y) * inv,
                      (accO[dsub][4 * q4 + 2] + ov.z) * inv,
                      (accO[dsub][4 * q4 + 3] + ov.w) * inv};
          *(f32x4*)ptr = vv;
        }
      // transposed coalesced store: 4 full q-rows per instruction
#pragma unroll
      for (int jj = 0; jj < 8; ++jj) {
        const int qq = jj * 4 + (lane >> 4);
        const int d0 = (lane & 15) * 4;
        f32x4 ov = *(const f32x4*)&scbO[(size_t)qq * SCSTR + d0];
        float* op = O + (((size_t)b * L_ + qt * 64 + 32 * s + qq) * H_ + h) * E_ + d0;
        *(f32x4*)op = ov;
      }
    }
  }
}

extern "C" void kernel_launch(void* const* d_in, const int* in_sizes, int n_in,
                              void* d_out, int out_size, void* d_ws, size_t ws_size,
                              hipStream_t stream) {
  (void)in_sizes; (void)n_in; (void)out_size; (void)ws_size;
  const float* Q = (const float*)d_in[0];
  const float* K = (const float*)d_in[1];
  const float* V = (const float*)d_in[2];
  float* Out = (float*)d_out;
  short* Kb = (short*)d_ws;                              // 16.78 MB
  short* Vt = Kb + (size_t)B_ * H_ * L_ * E_;            // +16.78 MB

  prep<<<1024 + 2048, 256, 0, stream>>>(K, V, Kb, Vt);
  flash_fwd<<<1024, 256, 0, stream>>>(Q, Kb, Vt, Out);
}